// Round 10
// baseline (1494.205 us; speedup 1.0000x reference)
//
#include <hip/hip_runtime.h>
#include <hip/hip_fp16.h>

// reaction_diffusion, 4-kernel pipeline:
//   1. transpose: x[64,N] -> xth[N,64] fp16 (+ zero gcur)
//   2. partition: dual-side bucket multisplit (512 thr, 2 blocks/CU, ONE round)
//   3. accgather: one block per (side, 128-node bucket); waves stream the
//      unsorted run, gather xth rows (scalar base + lane), ds_add_f32 into a
//      32KB LDS accumulator acc[dl][lane]. No sort, no counting, no conflicts.
//      782 jobs / (4 blocks/CU * 256 CU = 1024 slots) -> ONE round.
//   4. final: out[b,v] = tanh(colr*x - msgr + br) + (cold*x - msgd + bd) + x
// side 0 (dest = ei): w_main=wr -> msgr, w_col=wd -> cold
// side 1 (dest = ej): w_main=wd -> msgd, w_col=wr -> colr
// payload int2: x=(bkt:9<<23)|(dl:7<<16)|(other:16), y=bf16(wm)<<16|bf16(wc)
// requires N <= 65536 (other packed in 16 bits)

#define BKT_SHIFT 7
#define BKT_NODES 128
#define RCAP 4608     // per-(side,bucket) run capacity: mean 4096, +8 sigma
#define CH 4096       // partition chunk size (= 8 * 512 threads)
#define NBP 512       // padded per-side bin count (N <= 65536)

#define RFL(x) __builtin_amdgcn_readfirstlane(x)

__device__ __forceinline__ unsigned bf16_rne(float f) {
    unsigned u = __float_as_uint(f);
    unsigned rb = (u >> 16) & 1u;
    u += 0x7FFFu + rb;
    return u >> 16;
}
__device__ __forceinline__ float bf16_lo(int y) {
    return __uint_as_float(((unsigned)y) << 16);
}
__device__ __forceinline__ float bf16_hi(int y) {
    return __uint_as_float((unsigned)y & 0xFFFF0000u);
}

// kernel 1: x [64,N] -> xth [N,64] fp16; block 0 also zeroes gcur.
__global__ void transpose_kernel(const float* __restrict__ x, __half* __restrict__ xth,
                                 int* __restrict__ gcur, int ngcur, int N) {
    __shared__ float tile[64][65];
    int v0 = blockIdx.x * 64;
    int tx = threadIdx.x;   // 0..63
    int ty = threadIdx.y;   // 0..15
    int flat = blockIdx.x * 1024 + ty * 64 + tx;
    if (flat < ngcur) gcur[flat] = 0;
    if (v0 + tx < N) {
        for (int b = ty; b < 64; b += 16)
            tile[tx][b] = x[b * N + v0 + tx];
    }
    __syncthreads();
    for (int vl = ty; vl < 64; vl += 16) {
        int v = v0 + vl;
        if (v < N)
            xth[(size_t)v * 64 + tx] = __float2half(tile[vl][tx]);
    }
}

// kernel 2: dual-side chunked multi-split; edges in registers (read once).
// 512 thr, 76 KB LDS -> 2 blocks/CU -> 512 slots >= 391 chunks: ONE round.
__global__ void __launch_bounds__(512) partition_kernel(
        const int* __restrict__ ei, const int* __restrict__ ej,
        const float* __restrict__ wr, const float* __restrict__ wd,
        int* __restrict__ gcur, int2* __restrict__ runs,
        int E, int NB) {
    __shared__ int cnt[2 * NBP];     // 4 KB
    __shared__ int base_a[2 * NBP];  // 4 KB
    __shared__ int gb[2 * NBP];      // 4 KB
    __shared__ int2 buf[2 * CH];     // 64 KB

    int tid = threadIdx.x;
    int e0 = blockIdx.x * CH;
    int ch_len = min(CH, E - e0);
    if (ch_len <= 0) return;

    // load my 8 edges into registers
    int my_i[8], my_j[8];
    unsigned my_w[8];
    #pragma unroll
    for (int k = 0; k < 8; ++k) {
        int t = tid + k * 512;
        if (t < ch_len) {
            int e = e0 + t;
            my_i[k] = ei[e];
            my_j[k] = ej[e];
            my_w[k] = (bf16_rne(wr[e]) << 16) | bf16_rne(wd[e]);
        } else {
            my_i[k] = -1;
        }
    }

    for (int b = tid; b < 2 * NBP; b += 512) cnt[b] = 0;
    __syncthreads();
    #pragma unroll
    for (int k = 0; k < 8; ++k) {
        if (my_i[k] >= 0) {
            atomicAdd(&cnt[my_i[k] >> BKT_SHIFT], 1);
            atomicAdd(&cnt[NBP + (my_j[k] >> BKT_SHIFT)], 1);
        }
    }
    __syncthreads();
    if (tid < 64) {
        int carry = 0;
        #pragma unroll
        for (int c = 0; c < (2 * NBP) / 64; ++c) {
            int idx = c * 64 + tid;
            int val = cnt[idx];
            int scan = val;
            for (int off = 1; off < 64; off <<= 1) {
                int n = __shfl_up(scan, off, 64);
                if (tid >= off) scan += n;
            }
            int excl = scan - val + carry;
            base_a[idx] = excl;
            cnt[idx] = excl;            // becomes cursor
            carry += __shfl(scan, 63, 64);
        }
    }
    __syncthreads();
    #pragma unroll
    for (int k = 0; k < 8; ++k) {
        if (my_i[k] >= 0) {
            int i = my_i[k], j = my_j[k];
            unsigned wv = my_w[k];
            int b0 = i >> BKT_SHIFT;
            int p0 = atomicAdd(&cnt[b0], 1);
            buf[p0] = make_int2((int)(((unsigned)b0 << 23) | ((unsigned)(i & 127) << 16) | (unsigned)j),
                                (int)wv);
            int b1 = j >> BKT_SHIFT;
            int p1 = atomicAdd(&cnt[NBP + b1], 1);
            buf[p1] = make_int2((int)(((unsigned)b1 << 23) | ((unsigned)(j & 127) << 16) | (unsigned)i),
                                (int)((wv << 16) | (wv >> 16)));
        }
    }
    __syncthreads();
    for (int cb = tid; cb < 2 * NBP; cb += 512) {
        int n = cnt[cb] - base_a[cb];
        if (n > 0) {
            int side = cb >> 9;
            int bkt = cb & (NBP - 1);
            gb[cb] = atomicAdd(&gcur[side * NB + bkt], n);
        }
    }
    __syncthreads();
    int total = 2 * ch_len;
    for (int t = tid; t < total; t += 512) {
        int2 p = buf[t];
        int side = (t >= ch_len) ? 1 : 0;
        int bkt = ((unsigned)p.x >> 23) & 0x1FF;
        int cb = side * NBP + bkt;
        int rank = gb[cb] + (t - base_a[cb]);
        if (rank < RCAP)
            runs[((size_t)(side * NB + bkt)) * RCAP + rank] = p;
    }
}

// one payload: wave-uniform unpack, per-lane gather, LDS accumulate.
__device__ __forceinline__ void pay_acc(int px, int py,
                                        const __half* __restrict__ xth,
                                        float* __restrict__ acc, float* __restrict__ cs,
                                        int lane) {
    int dl = ((unsigned)px >> 16) & 0x7F;
    int o = px & 0xFFFF;
    float wm = bf16_hi(py);
    float xv = __half2float(xth[((size_t)o << 6) + lane]);
    atomicAdd(&acc[(dl << 6) + lane], wm * xv);
    if (lane == 0) atomicAdd(&cs[dl], bf16_lo(py));
}

// kernel 3: one block per (side,bucket): stream unsorted run, accumulate in LDS.
__global__ void __launch_bounds__(512) accgather_kernel(
        const int* __restrict__ gcur, const int2* __restrict__ runs,
        const __half* __restrict__ xth,
        __half* __restrict__ msg, float* __restrict__ colsum,
        int NB, int N) {
    __shared__ float acc[BKT_NODES * 64];   // 32 KB
    __shared__ float cs[BKT_NODES];         // 0.5 KB

    int sb = blockIdx.x;               // side*NB + b
    int side = (sb >= NB) ? 1 : 0;
    int b = sb - side * NB;
    int v0 = b << BKT_SHIFT;
    int len = min(gcur[sb], RCAP);
    int tid = threadIdx.x;
    int lane = tid & 63;
    int wid = tid >> 6;                // 0..7

    for (int k = tid; k < BKT_NODES * 64; k += 512) acc[k] = 0.f;
    if (tid < BKT_NODES) cs[tid] = 0.f;
    __syncthreads();

    // stream the run as int4 quads (2 payloads each), waves strided over quads
    const int4* quads = (const int4*)(runs + (size_t)sb * RCAP);
    int nq = (len + 1) >> 1;
    int q = wid;
    for (; q + 16 < nq; q += 16) {     // full pairs: no bounds checks
        int4 qa = quads[q];
        int4 qb = quads[q + 8];
        pay_acc(RFL(qa.x), RFL(qa.y), xth, acc, cs, lane);
        pay_acc(RFL(qa.z), RFL(qa.w), xth, acc, cs, lane);
        pay_acc(RFL(qb.x), RFL(qb.y), xth, acc, cs, lane);
        pay_acc(RFL(qb.z), RFL(qb.w), xth, acc, cs, lane);
    }
    for (; q < nq; q += 8) {
        int4 qa = quads[q];
        pay_acc(RFL(qa.x), RFL(qa.y), xth, acc, cs, lane);
        if (2 * q + 1 < len)
            pay_acc(RFL(qa.z), RFL(qa.w), xth, acc, cs, lane);
    }
    __syncthreads();

    // epilogue: write msg fp16 rows + colsum
    for (int flat = tid; flat < BKT_NODES * 64; flat += 512) {
        int dl = flat >> 6;
        int v = v0 + dl;
        if (v < N)
            msg[((size_t)side * N + v) * 64 + (flat & 63)] = __float2half(acc[flat]);
    }
    if (tid < BKT_NODES) {
        int v = v0 + tid;
        if (v < N)
            colsum[(size_t)side * N + v] = cs[tid];
    }
}

// kernel 4: epilogue from original x [64,N]; LDS-transpose fp16 msg tiles.
__global__ void final_kernel(const float* __restrict__ x,
                             const __half* __restrict__ msg,
                             const float* __restrict__ colsum,
                             const float* __restrict__ br, const float* __restrict__ bd,
                             float* __restrict__ out, int N) {
    __shared__ float tr[64][65];
    __shared__ float td[64][65];
    int v0 = blockIdx.x * 64;
    int tx = threadIdx.x;
    int ty = threadIdx.y;
    for (int vl = ty; vl < 64; vl += 16) {
        int v = v0 + vl;
        if (v < N) {
            tr[vl][tx] = __half2float(msg[(size_t)v * 64 + tx]);               // msgr
            td[vl][tx] = __half2float(msg[((size_t)N + v) * 64 + tx]);         // msgd
        }
    }
    __syncthreads();
    int v = v0 + tx;
    if (v < N) {
        float cold = colsum[v];              // side 0: sum wd over e: ei=v
        float colr = colsum[(size_t)N + v];  // side 1: sum wr over e: ej=v
        float brv = br[v], bdv = bd[v];
        for (int b = ty; b < 64; b += 16) {
            float xv = x[b * N + v];
            float r = colr * xv - tr[tx][b] + brv;
            float d = cold * xv - td[tx][b] + bdv;
            out[b * N + v] = tanhf(r) + d + xv;
        }
    }
}

extern "C" void kernel_launch(void* const* d_in, const int* in_sizes, int n_in,
                              void* d_out, int out_size, void* d_ws, size_t ws_size,
                              hipStream_t stream) {
    const float* x  = (const float*)d_in[1];
    const int*   ei = (const int*)d_in[2];
    const int*   ej = (const int*)d_in[3];
    const float* wr = (const float*)d_in[4];
    const float* wd = (const float*)d_in[5];
    const float* br = (const float*)d_in[6];
    const float* bd = (const float*)d_in[7];
    float* out = (float*)d_out;

    int E = in_sizes[2];
    int N = in_sizes[6];
    int NB = (N + BKT_NODES - 1) >> BKT_SHIFT;
    (void)out_size; (void)ws_size; (void)n_in;

    // workspace: xth[N*64 f16] | msg[2*N*64 f16] | colsum[2N f32] | gcur[2NB]
    //          | runs[2*NB*RCAP int2]   (~48 MB)
    char* w = (char*)d_ws;
    __half* xth = (__half*)w;    w += (size_t)N * 64 * 2;
    __half* msg = (__half*)w;    w += (size_t)2 * N * 64 * 2;
    float* colsum = (float*)w;   w += (size_t)2 * N * 4;
    int* gcur   = (int*)w;       w += (size_t)2 * NB * 4;
    w = (char*)(((uintptr_t)w + 15) & ~(uintptr_t)15);
    int2* runs  = (int2*)w;

    dim3 tb(64, 16);
    int ntiles = (N + 63) / 64;
    transpose_kernel<<<ntiles, tb, 0, stream>>>(x, xth, gcur, 2 * NB, N);

    int nchunks = (E + CH - 1) / CH;
    partition_kernel<<<nchunks, 512, 0, stream>>>(ei, ej, wr, wd, gcur, runs, E, NB);

    accgather_kernel<<<2 * NB, 512, 0, stream>>>(gcur, runs, xth, msg, colsum, NB, N);

    final_kernel<<<ntiles, tb, 0, stream>>>(x, msg, colsum, br, bd, out, N);
}

// Round 11
// 208.718 us; speedup vs baseline: 7.1590x; 7.1590x over previous
//
#include <hip/hip_runtime.h>
#include <hip/hip_fp16.h>

// reaction_diffusion, 4-kernel pipeline (geometry-tuned):
//   1. transpose: x[64,N] -> xth[N,64] fp16 (+ zero gcur)
//   2. partition: dual-side bucket multisplit (512 thr, 76KB LDS, 2 blocks/CU,
//      391 chunks <= 512 slots: ONE round)
//   3. sortgather: one 512-thr block per (side,bucket), ~22KB LDS -> 4 blocks/CU,
//      782 jobs <= 1024 slots: ONE round. Two global passes over the run
//      (count+colsum, place-sorted-into-LDS), then in-LDS payload gather with
//      scalar (SGPR) addressing, register accumulate, fp16 msg write.
//   4. final: out[b,v] = tanh(colr*x - msgr + br) + (cold*x - msgd + bd) + x
// side 0 (dest = ei): w_main=wr -> msgr, w_col=wd -> cold
// side 1 (dest = ej): w_main=wd -> msgd, w_col=wr -> colr
// stage-1 payload int2: x=(bkt:9<<23)|(dl:7<<16)|(other:16), y=bf16(wm)<<16|bf16(wc)
// sorted payload int: (bf16(wm)<<16)|other:16   -- requires N <= 65536
// LDS f32 atomics: ONLY ~1 lane-op per payload (per-lane serialized RMW on
// gfx950, ~270cy per wave-wide op -- R4/R10 post-mortem). Never per-lane-wide.

#define BKT_SHIFT 7
#define BKT_NODES 128
#define RCAP 4608     // per-(side,bucket) run capacity: mean 4096, +8 sigma
#define RCAP2 4992    // quad-padded bound (4608 + 128*3)
#define CH 4096       // partition chunk size (= 8 * 512 threads)
#define NBP 512       // padded per-side bin count (N <= 65536)

#define RFL(x) __builtin_amdgcn_readfirstlane(x)

__device__ __forceinline__ unsigned bf16_rne(float f) {
    unsigned u = __float_as_uint(f);
    unsigned rb = (u >> 16) & 1u;
    u += 0x7FFFu + rb;
    return u >> 16;
}
__device__ __forceinline__ float bf16_lo(int y) {
    return __uint_as_float(((unsigned)y) << 16);
}
__device__ __forceinline__ float bf16_hi(int y) {
    return __uint_as_float((unsigned)y & 0xFFFF0000u);
}

// kernel 1: x [64,N] -> xth [N,64] fp16; also zeroes gcur.
__global__ void transpose_kernel(const float* __restrict__ x, __half* __restrict__ xth,
                                 int* __restrict__ gcur, int ngcur, int N) {
    __shared__ float tile[64][65];
    int v0 = blockIdx.x * 64;
    int tx = threadIdx.x;   // 0..63
    int ty = threadIdx.y;   // 0..15
    int flat = blockIdx.x * 1024 + ty * 64 + tx;
    if (flat < ngcur) gcur[flat] = 0;
    if (v0 + tx < N) {
        for (int b = ty; b < 64; b += 16)
            tile[tx][b] = x[b * N + v0 + tx];
    }
    __syncthreads();
    for (int vl = ty; vl < 64; vl += 16) {
        int v = v0 + vl;
        if (v < N)
            xth[(size_t)v * 64 + tx] = __float2half(tile[vl][tx]);
    }
}

// kernel 2: dual-side chunked multi-split; edges in registers (read once).
__global__ void __launch_bounds__(512) partition_kernel(
        const int* __restrict__ ei, const int* __restrict__ ej,
        const float* __restrict__ wr, const float* __restrict__ wd,
        int* __restrict__ gcur, int2* __restrict__ runs,
        int E, int NB) {
    __shared__ int cnt[2 * NBP];     // 4 KB
    __shared__ int base_a[2 * NBP];  // 4 KB
    __shared__ int gb[2 * NBP];      // 4 KB
    __shared__ int2 buf[2 * CH];     // 64 KB

    int tid = threadIdx.x;
    int e0 = blockIdx.x * CH;
    int ch_len = min(CH, E - e0);
    if (ch_len <= 0) return;

    int my_i[8], my_j[8];
    unsigned my_w[8];
    #pragma unroll
    for (int k = 0; k < 8; ++k) {
        int t = tid + k * 512;
        if (t < ch_len) {
            int e = e0 + t;
            my_i[k] = ei[e];
            my_j[k] = ej[e];
            my_w[k] = (bf16_rne(wr[e]) << 16) | bf16_rne(wd[e]);
        } else {
            my_i[k] = -1;
        }
    }

    for (int b = tid; b < 2 * NBP; b += 512) cnt[b] = 0;
    __syncthreads();
    #pragma unroll
    for (int k = 0; k < 8; ++k) {
        if (my_i[k] >= 0) {
            atomicAdd(&cnt[my_i[k] >> BKT_SHIFT], 1);
            atomicAdd(&cnt[NBP + (my_j[k] >> BKT_SHIFT)], 1);
        }
    }
    __syncthreads();
    if (tid < 64) {
        int carry = 0;
        #pragma unroll
        for (int c = 0; c < (2 * NBP) / 64; ++c) {
            int idx = c * 64 + tid;
            int val = cnt[idx];
            int scan = val;
            for (int off = 1; off < 64; off <<= 1) {
                int n = __shfl_up(scan, off, 64);
                if (tid >= off) scan += n;
            }
            int excl = scan - val + carry;
            base_a[idx] = excl;
            cnt[idx] = excl;            // becomes cursor
            carry += __shfl(scan, 63, 64);
        }
    }
    __syncthreads();
    #pragma unroll
    for (int k = 0; k < 8; ++k) {
        if (my_i[k] >= 0) {
            int i = my_i[k], j = my_j[k];
            unsigned wv = my_w[k];
            int b0 = i >> BKT_SHIFT;
            int p0 = atomicAdd(&cnt[b0], 1);
            buf[p0] = make_int2((int)(((unsigned)b0 << 23) | ((unsigned)(i & 127) << 16) | (unsigned)j),
                                (int)wv);
            int b1 = j >> BKT_SHIFT;
            int p1 = atomicAdd(&cnt[NBP + b1], 1);
            buf[p1] = make_int2((int)(((unsigned)b1 << 23) | ((unsigned)(j & 127) << 16) | (unsigned)i),
                                (int)((wv << 16) | (wv >> 16)));
        }
    }
    __syncthreads();
    for (int cb = tid; cb < 2 * NBP; cb += 512) {
        int n = cnt[cb] - base_a[cb];
        if (n > 0) {
            int side = cb >> 9;
            int bkt = cb & (NBP - 1);
            gb[cb] = atomicAdd(&gcur[side * NB + bkt], n);
        }
    }
    __syncthreads();
    int total = 2 * ch_len;
    for (int t = tid; t < total; t += 512) {
        int2 p = buf[t];
        int side = (t >= ch_len) ? 1 : 0;
        int bkt = ((unsigned)p.x >> 23) & 0x1FF;
        int cb = side * NBP + bkt;
        int rank = gb[cb] + (t - base_a[cb]);
        if (rank < RCAP)
            runs[((size_t)(side * NB + bkt)) * RCAP + rank] = p;
    }
}

// kernel 3: per (side,bucket): two global passes (count, place) -> sorted LDS
// payloads -> in-LDS gather with scalar addressing. ~22 KB LDS, 512 thr.
__global__ void __launch_bounds__(512) sortgather_kernel(
        const int* __restrict__ gcur, const int2* __restrict__ runs,
        const __half* __restrict__ xth,
        __half* __restrict__ msg, float* __restrict__ colsum,
        int NB, int N) {
    __shared__ int cnt[BKT_NODES];
    __shared__ int cur[BKT_NODES];
    __shared__ int pb[BKT_NODES];
    __shared__ float csum[BKT_NODES];
    __shared__ int dst[RCAP2];                  // 19.5 KB

    int sb = blockIdx.x;               // side*NB + b
    int side = (sb >= NB) ? 1 : 0;
    int b = sb - side * NB;
    int v0 = b << BKT_SHIFT;
    int len = min(gcur[sb], RCAP);
    size_t roff = (size_t)sb * RCAP;
    int tid = threadIdx.x;

    if (tid < BKT_NODES) { cnt[tid] = 0; csum[tid] = 0.f; }
    __syncthreads();
    // pass A: count + column sums (1 int + 1 f32 LDS atomic lane-op per payload)
    for (int k = tid; k < len; k += 512) {
        int2 p = runs[roff + k];
        int dl = ((unsigned)p.x >> 16) & 0x7F;
        atomicAdd(&cnt[dl], 1);
        atomicAdd(&csum[dl], bf16_lo(p.y));
    }
    __syncthreads();
    if (tid < 64) {
        int carry = 0;
        #pragma unroll
        for (int c = 0; c < BKT_NODES / 64; ++c) {
            int idx = c * 64 + tid;
            int val = (cnt[idx] + 3) & ~3;       // quad-padded
            int scan = val;
            for (int off = 1; off < 64; off <<= 1) {
                int n = __shfl_up(scan, off, 64);
                if (tid >= off) scan += n;
            }
            int excl = scan - val + carry;
            pb[idx] = excl;
            cur[idx] = excl;
            carry += __shfl(scan, 63, 64);
        }
    }
    __syncthreads();
    if (tid < BKT_NODES) {
        int pc = (cnt[tid] + 3) & ~3;
        for (int t = cnt[tid]; t < pc; ++t) dst[pb[tid] + t] = 0;   // zero pads
    }
    __syncthreads();
    // pass B: place compact payloads sorted by dest node (L2-hot re-read)
    for (int k = tid; k < len; k += 512) {
        int2 p = runs[roff + k];
        int dl = ((unsigned)p.x >> 16) & 0x7F;
        int pos = atomicAdd(&cur[dl], 1);
        dst[pos] = (int)(((unsigned)p.y & 0xFFFF0000u) | ((unsigned)p.x & 0xFFFFu));
    }
    __syncthreads();

    // gather: wave w owns nodes dl = w*16 .. w*16+15; scalar-uniform payloads,
    // per-lane work = one fp16 row load + fmac per payload.
    int lane = tid & 63;
    int wid = tid >> 6;
    for (int t = 0; t < BKT_NODES / 8; ++t) {
        int dl = wid * (BKT_NODES / 8) + t;
        int v = v0 + dl;
        if (v >= N) continue;                       // wave-uniform
        int base = pb[dl];                          // quad-aligned
        int nq = (cnt[dl] + 3) >> 2;
        const int4* quads = (const int4*)(dst + base);
        float acc = 0.f;
        int q = 0;
        for (; q + 2 <= nq; q += 2) {
            int4 qa = quads[q];
            int4 qb = quads[q + 1];
            int p0 = RFL(qa.x), p1 = RFL(qa.y), p2 = RFL(qa.z), p3 = RFL(qa.w);
            int p4 = RFL(qb.x), p5 = RFL(qb.y), p6 = RFL(qb.z), p7 = RFL(qb.w);
            float x0 = __half2float(xth[((size_t)(p0 & 0xFFFF) << 6) + lane]);
            float x1 = __half2float(xth[((size_t)(p1 & 0xFFFF) << 6) + lane]);
            float x2 = __half2float(xth[((size_t)(p2 & 0xFFFF) << 6) + lane]);
            float x3 = __half2float(xth[((size_t)(p3 & 0xFFFF) << 6) + lane]);
            float x4 = __half2float(xth[((size_t)(p4 & 0xFFFF) << 6) + lane]);
            float x5 = __half2float(xth[((size_t)(p5 & 0xFFFF) << 6) + lane]);
            float x6 = __half2float(xth[((size_t)(p6 & 0xFFFF) << 6) + lane]);
            float x7 = __half2float(xth[((size_t)(p7 & 0xFFFF) << 6) + lane]);
            acc = fmaf(bf16_hi(p0), x0, acc);
            acc = fmaf(bf16_hi(p1), x1, acc);
            acc = fmaf(bf16_hi(p2), x2, acc);
            acc = fmaf(bf16_hi(p3), x3, acc);
            acc = fmaf(bf16_hi(p4), x4, acc);
            acc = fmaf(bf16_hi(p5), x5, acc);
            acc = fmaf(bf16_hi(p6), x6, acc);
            acc = fmaf(bf16_hi(p7), x7, acc);
        }
        if (q < nq) {
            int4 qa = quads[q];
            int p0 = RFL(qa.x), p1 = RFL(qa.y), p2 = RFL(qa.z), p3 = RFL(qa.w);
            float x0 = __half2float(xth[((size_t)(p0 & 0xFFFF) << 6) + lane]);
            float x1 = __half2float(xth[((size_t)(p1 & 0xFFFF) << 6) + lane]);
            float x2 = __half2float(xth[((size_t)(p2 & 0xFFFF) << 6) + lane]);
            float x3 = __half2float(xth[((size_t)(p3 & 0xFFFF) << 6) + lane]);
            acc = fmaf(bf16_hi(p0), x0, acc);
            acc = fmaf(bf16_hi(p1), x1, acc);
            acc = fmaf(bf16_hi(p2), x2, acc);
            acc = fmaf(bf16_hi(p3), x3, acc);
        }
        msg[((size_t)side * N + v) * 64 + lane] = __float2half(acc);
        if (lane == 0)
            colsum[(size_t)side * N + v] = csum[dl];
    }
}

// kernel 4: epilogue from original x [64,N]; LDS-transpose fp16 msg tiles.
__global__ void final_kernel(const float* __restrict__ x,
                             const __half* __restrict__ msg,
                             const float* __restrict__ colsum,
                             const float* __restrict__ br, const float* __restrict__ bd,
                             float* __restrict__ out, int N) {
    __shared__ float tr[64][65];
    __shared__ float td[64][65];
    int v0 = blockIdx.x * 64;
    int tx = threadIdx.x;
    int ty = threadIdx.y;
    for (int vl = ty; vl < 64; vl += 16) {
        int v = v0 + vl;
        if (v < N) {
            tr[vl][tx] = __half2float(msg[(size_t)v * 64 + tx]);               // msgr
            td[vl][tx] = __half2float(msg[((size_t)N + v) * 64 + tx]);         // msgd
        }
    }
    __syncthreads();
    int v = v0 + tx;
    if (v < N) {
        float cold = colsum[v];              // side 0: sum wd over e: ei=v
        float colr = colsum[(size_t)N + v];  // side 1: sum wr over e: ej=v
        float brv = br[v], bdv = bd[v];
        for (int b = ty; b < 64; b += 16) {
            float xv = x[b * N + v];
            float r = colr * xv - tr[tx][b] + brv;
            float d = cold * xv - td[tx][b] + bdv;
            out[b * N + v] = tanhf(r) + d + xv;
        }
    }
}

extern "C" void kernel_launch(void* const* d_in, const int* in_sizes, int n_in,
                              void* d_out, int out_size, void* d_ws, size_t ws_size,
                              hipStream_t stream) {
    const float* x  = (const float*)d_in[1];
    const int*   ei = (const int*)d_in[2];
    const int*   ej = (const int*)d_in[3];
    const float* wr = (const float*)d_in[4];
    const float* wd = (const float*)d_in[5];
    const float* br = (const float*)d_in[6];
    const float* bd = (const float*)d_in[7];
    float* out = (float*)d_out;

    int E = in_sizes[2];
    int N = in_sizes[6];
    int NB = (N + BKT_NODES - 1) >> BKT_SHIFT;
    (void)out_size; (void)ws_size; (void)n_in;

    // workspace: xth[N*64 f16] | msg[2*N*64 f16] | colsum[2N f32] | gcur[2NB]
    //          | runs[2*NB*RCAP int2]   (~48 MB)
    char* w = (char*)d_ws;
    __half* xth = (__half*)w;    w += (size_t)N * 64 * 2;
    __half* msg = (__half*)w;    w += (size_t)2 * N * 64 * 2;
    float* colsum = (float*)w;   w += (size_t)2 * N * 4;
    int* gcur   = (int*)w;       w += (size_t)2 * NB * 4;
    w = (char*)(((uintptr_t)w + 15) & ~(uintptr_t)15);
    int2* runs  = (int2*)w;

    dim3 tb(64, 16);
    int ntiles = (N + 63) / 64;
    transpose_kernel<<<ntiles, tb, 0, stream>>>(x, xth, gcur, 2 * NB, N);

    int nchunks = (E + CH - 1) / CH;
    partition_kernel<<<nchunks, 512, 0, stream>>>(ei, ej, wr, wd, gcur, runs, E, NB);

    sortgather_kernel<<<2 * NB, 512, 0, stream>>>(gcur, runs, xth, msg, colsum, NB, N);

    final_kernel<<<ntiles, tb, 0, stream>>>(x, msg, colsum, br, bd, out, N);
}

// Round 12
// 203.821 us; speedup vs baseline: 7.3310x; 1.0240x over previous
//
#include <hip/hip_runtime.h>
#include <hip/hip_fp16.h>

// reaction_diffusion, 4-kernel pipeline (R11 geometry + split-half gather):
//   1. transpose: x[64,N] -> xth[N,64] fp16 (+ zero gcur)
//   2. partition: dual-side bucket multisplit (512 thr, 76KB LDS, 2 blocks/CU,
//      391 chunks <= 512 slots: ONE round)
//   3. sortgather: one 512-thr block per (side,bucket), ~22KB LDS -> 4 blocks/CU,
//      782 jobs <= 1024 slots: ONE round. Sort passes as R11. Gather: lanes
//      0-31 even payload, 32-63 odd payload of each pair; each lane loads a
//      half2 (2 batches) -> one VMEM instr per TWO payloads; cross-half
//      shfl_xor combine; msg written as half2 by the low half-wave.
//   4. final: out[b,v] = tanh(colr*x - msgr + br) + (cold*x - msgd + bd) + x
// side 0 (dest = ei): w_main=wr -> msgr, w_col=wd -> cold
// side 1 (dest = ej): w_main=wd -> msgd, w_col=wr -> colr
// stage-1 payload int2: x=(bkt:9<<23)|(dl:7<<16)|(other:16), y=bf16(wm)<<16|bf16(wc)
// sorted payload int: (bf16(wm)<<16)|other:16   -- requires N <= 65536
// LDS f32 atomics: only ~1 lane-op per payload (R4/R10 post-mortem: wave-wide
// ds f32 atomics serialize ~270cy/instr). Never per-payload-wave-wide.

#define BKT_SHIFT 7
#define BKT_NODES 128
#define RCAP 4608     // per-(side,bucket) run capacity: mean 4096, +8 sigma
#define RCAP2 4992    // quad-padded bound (4608 + 128*3)
#define CH 4096       // partition chunk size (= 8 * 512 threads)
#define NBP 512       // padded per-side bin count (N <= 65536)

#define RFL(x) __builtin_amdgcn_readfirstlane(x)

__device__ __forceinline__ unsigned bf16_rne(float f) {
    unsigned u = __float_as_uint(f);
    unsigned rb = (u >> 16) & 1u;
    u += 0x7FFFu + rb;
    return u >> 16;
}
__device__ __forceinline__ float bf16_lo(int y) {
    return __uint_as_float(((unsigned)y) << 16);
}
__device__ __forceinline__ float bf16_hi(int y) {
    return __uint_as_float((unsigned)y & 0xFFFF0000u);
}

// kernel 1: x [64,N] -> xth [N,64] fp16; also zeroes gcur.
__global__ void transpose_kernel(const float* __restrict__ x, __half* __restrict__ xth,
                                 int* __restrict__ gcur, int ngcur, int N) {
    __shared__ float tile[64][65];
    int v0 = blockIdx.x * 64;
    int tx = threadIdx.x;   // 0..63
    int ty = threadIdx.y;   // 0..15
    int flat = blockIdx.x * 1024 + ty * 64 + tx;
    if (flat < ngcur) gcur[flat] = 0;
    if (v0 + tx < N) {
        for (int b = ty; b < 64; b += 16)
            tile[tx][b] = x[b * N + v0 + tx];
    }
    __syncthreads();
    for (int vl = ty; vl < 64; vl += 16) {
        int v = v0 + vl;
        if (v < N)
            xth[(size_t)v * 64 + tx] = __float2half(tile[vl][tx]);
    }
}

// kernel 2: dual-side chunked multi-split; edges in registers (read once).
__global__ void __launch_bounds__(512) partition_kernel(
        const int* __restrict__ ei, const int* __restrict__ ej,
        const float* __restrict__ wr, const float* __restrict__ wd,
        int* __restrict__ gcur, int2* __restrict__ runs,
        int E, int NB) {
    __shared__ int cnt[2 * NBP];     // 4 KB
    __shared__ int base_a[2 * NBP];  // 4 KB
    __shared__ int gb[2 * NBP];      // 4 KB
    __shared__ int2 buf[2 * CH];     // 64 KB

    int tid = threadIdx.x;
    int e0 = blockIdx.x * CH;
    int ch_len = min(CH, E - e0);
    if (ch_len <= 0) return;

    int my_i[8], my_j[8];
    unsigned my_w[8];
    #pragma unroll
    for (int k = 0; k < 8; ++k) {
        int t = tid + k * 512;
        if (t < ch_len) {
            int e = e0 + t;
            my_i[k] = ei[e];
            my_j[k] = ej[e];
            my_w[k] = (bf16_rne(wr[e]) << 16) | bf16_rne(wd[e]);
        } else {
            my_i[k] = -1;
        }
    }

    for (int b = tid; b < 2 * NBP; b += 512) cnt[b] = 0;
    __syncthreads();
    #pragma unroll
    for (int k = 0; k < 8; ++k) {
        if (my_i[k] >= 0) {
            atomicAdd(&cnt[my_i[k] >> BKT_SHIFT], 1);
            atomicAdd(&cnt[NBP + (my_j[k] >> BKT_SHIFT)], 1);
        }
    }
    __syncthreads();
    if (tid < 64) {
        int carry = 0;
        #pragma unroll
        for (int c = 0; c < (2 * NBP) / 64; ++c) {
            int idx = c * 64 + tid;
            int val = cnt[idx];
            int scan = val;
            for (int off = 1; off < 64; off <<= 1) {
                int n = __shfl_up(scan, off, 64);
                if (tid >= off) scan += n;
            }
            int excl = scan - val + carry;
            base_a[idx] = excl;
            cnt[idx] = excl;            // becomes cursor
            carry += __shfl(scan, 63, 64);
        }
    }
    __syncthreads();
    #pragma unroll
    for (int k = 0; k < 8; ++k) {
        if (my_i[k] >= 0) {
            int i = my_i[k], j = my_j[k];
            unsigned wv = my_w[k];
            int b0 = i >> BKT_SHIFT;
            int p0 = atomicAdd(&cnt[b0], 1);
            buf[p0] = make_int2((int)(((unsigned)b0 << 23) | ((unsigned)(i & 127) << 16) | (unsigned)j),
                                (int)wv);
            int b1 = j >> BKT_SHIFT;
            int p1 = atomicAdd(&cnt[NBP + b1], 1);
            buf[p1] = make_int2((int)(((unsigned)b1 << 23) | ((unsigned)(j & 127) << 16) | (unsigned)i),
                                (int)((wv << 16) | (wv >> 16)));
        }
    }
    __syncthreads();
    for (int cb = tid; cb < 2 * NBP; cb += 512) {
        int n = cnt[cb] - base_a[cb];
        if (n > 0) {
            int side = cb >> 9;
            int bkt = cb & (NBP - 1);
            gb[cb] = atomicAdd(&gcur[side * NB + bkt], n);
        }
    }
    __syncthreads();
    int total = 2 * ch_len;
    for (int t = tid; t < total; t += 512) {
        int2 p = buf[t];
        int side = (t >= ch_len) ? 1 : 0;
        int bkt = ((unsigned)p.x >> 23) & 0x1FF;
        int cb = side * NBP + bkt;
        int rank = gb[cb] + (t - base_a[cb]);
        if (rank < RCAP)
            runs[((size_t)(side * NB + bkt)) * RCAP + rank] = p;
    }
}

// kernel 3: per (side,bucket): two global passes (count, place) -> sorted LDS
// payloads -> split-half gather. ~22 KB LDS, 512 thr, 4 blocks/CU.
__global__ void __launch_bounds__(512) sortgather_kernel(
        const int* __restrict__ gcur, const int2* __restrict__ runs,
        const __half* __restrict__ xth,
        __half* __restrict__ msg, float* __restrict__ colsum,
        int NB, int N) {
    __shared__ int cnt[BKT_NODES];
    __shared__ int cur[BKT_NODES];
    __shared__ int pb[BKT_NODES];
    __shared__ float csum[BKT_NODES];
    __shared__ int dst[RCAP2];                  // 19.5 KB

    int sb = blockIdx.x;               // side*NB + b
    int side = (sb >= NB) ? 1 : 0;
    int b = sb - side * NB;
    int v0 = b << BKT_SHIFT;
    int len = min(gcur[sb], RCAP);
    size_t roff = (size_t)sb * RCAP;
    int tid = threadIdx.x;

    if (tid < BKT_NODES) { cnt[tid] = 0; csum[tid] = 0.f; }
    __syncthreads();
    // pass A: count + column sums (1 int + 1 f32 LDS atomic lane-op per payload)
    for (int k = tid; k < len; k += 512) {
        int2 p = runs[roff + k];
        int dl = ((unsigned)p.x >> 16) & 0x7F;
        atomicAdd(&cnt[dl], 1);
        atomicAdd(&csum[dl], bf16_lo(p.y));
    }
    __syncthreads();
    if (tid < 64) {
        int carry = 0;
        #pragma unroll
        for (int c = 0; c < BKT_NODES / 64; ++c) {
            int idx = c * 64 + tid;
            int val = (cnt[idx] + 3) & ~3;       // quad-padded
            int scan = val;
            for (int off = 1; off < 64; off <<= 1) {
                int n = __shfl_up(scan, off, 64);
                if (tid >= off) scan += n;
            }
            int excl = scan - val + carry;
            pb[idx] = excl;
            cur[idx] = excl;
            carry += __shfl(scan, 63, 64);
        }
    }
    __syncthreads();
    if (tid < BKT_NODES) {
        int pc = (cnt[tid] + 3) & ~3;
        for (int t = cnt[tid]; t < pc; ++t) dst[pb[tid] + t] = 0;   // zero pads
    }
    __syncthreads();
    // pass B: place compact payloads sorted by dest node (L2-hot re-read)
    for (int k = tid; k < len; k += 512) {
        int2 p = runs[roff + k];
        int dl = ((unsigned)p.x >> 16) & 0x7F;
        int pos = atomicAdd(&cur[dl], 1);
        dst[pos] = (int)(((unsigned)p.y & 0xFFFF0000u) | ((unsigned)p.x & 0xFFFFu));
    }
    __syncthreads();

    // gather: wave w owns nodes dl = w*16..w*16+15. Split halves: lanes 0-31
    // process even payloads, lanes 32-63 odd; each lane covers 2 batches via
    // half2 dword loads. One VMEM instr per TWO payloads.
    const unsigned* __restrict__ xth2 = (const unsigned*)xth;  // [N][32] dwords
    int lane = tid & 63;
    int halfl = lane & 31;
    int hi = lane >> 5;                 // 0 or 1
    int wid = tid >> 6;
    for (int t = 0; t < BKT_NODES / 8; ++t) {
        int dl = wid * (BKT_NODES / 8) + t;
        int v = v0 + dl;
        if (v >= N) continue;                       // wave-uniform
        const int* pay = dst + pb[dl] + hi;         // this half's payload lane
        int npair = ((cnt[dl] + 3) & ~3) >> 1;      // even (quad pad -> pair pad)
        float a0 = 0.f, a1 = 0.f;
        int q = 0;
        for (; q + 4 <= npair; q += 4) {
            int pA = pay[2 * q];
            int pB = pay[2 * q + 2];
            int pC = pay[2 * q + 4];
            int pD = pay[2 * q + 6];
            unsigned dA = xth2[(((size_t)((unsigned)pA & 0xFFFFu)) << 5) + halfl];
            unsigned dB = xth2[(((size_t)((unsigned)pB & 0xFFFFu)) << 5) + halfl];
            unsigned dC = xth2[(((size_t)((unsigned)pC & 0xFFFFu)) << 5) + halfl];
            unsigned dD = xth2[(((size_t)((unsigned)pD & 0xFFFFu)) << 5) + halfl];
            float wA = bf16_hi(pA), wB = bf16_hi(pB);
            float wC = bf16_hi(pC), wD = bf16_hi(pD);
            float2 xA = __half22float2(*(const __half2*)&dA);
            float2 xB = __half22float2(*(const __half2*)&dB);
            float2 xC = __half22float2(*(const __half2*)&dC);
            float2 xD = __half22float2(*(const __half2*)&dD);
            a0 = fmaf(wA, xA.x, a0); a1 = fmaf(wA, xA.y, a1);
            a0 = fmaf(wB, xB.x, a0); a1 = fmaf(wB, xB.y, a1);
            a0 = fmaf(wC, xC.x, a0); a1 = fmaf(wC, xC.y, a1);
            a0 = fmaf(wD, xD.x, a0); a1 = fmaf(wD, xD.y, a1);
        }
        for (; q < npair; ++q) {
            int p = pay[2 * q];
            unsigned d = xth2[(((size_t)((unsigned)p & 0xFFFFu)) << 5) + halfl];
            float wv = bf16_hi(p);
            float2 xf = __half22float2(*(const __half2*)&d);
            a0 = fmaf(wv, xf.x, a0);
            a1 = fmaf(wv, xf.y, a1);
        }
        // combine even-half and odd-half partial sums
        a0 += __shfl_xor(a0, 32);
        a1 += __shfl_xor(a1, 32);
        if (hi == 0) {
            __half2 h = __floats2half2_rn(a0, a1);
            *(__half2*)(msg + ((size_t)side * N + v) * 64 + 2 * halfl) = h;
        }
        if (lane == 0)
            colsum[(size_t)side * N + v] = csum[dl];
    }
}

// kernel 4: epilogue from original x [64,N]; LDS-transpose fp16 msg tiles.
__global__ void final_kernel(const float* __restrict__ x,
                             const __half* __restrict__ msg,
                             const float* __restrict__ colsum,
                             const float* __restrict__ br, const float* __restrict__ bd,
                             float* __restrict__ out, int N) {
    __shared__ float tr[64][65];
    __shared__ float td[64][65];
    int v0 = blockIdx.x * 64;
    int tx = threadIdx.x;
    int ty = threadIdx.y;
    for (int vl = ty; vl < 64; vl += 16) {
        int v = v0 + vl;
        if (v < N) {
            tr[vl][tx] = __half2float(msg[(size_t)v * 64 + tx]);               // msgr
            td[vl][tx] = __half2float(msg[((size_t)N + v) * 64 + tx]);         // msgd
        }
    }
    __syncthreads();
    int v = v0 + tx;
    if (v < N) {
        float cold = colsum[v];              // side 0: sum wd over e: ei=v
        float colr = colsum[(size_t)N + v];  // side 1: sum wr over e: ej=v
        float brv = br[v], bdv = bd[v];
        for (int b = ty; b < 64; b += 16) {
            float xv = x[b * N + v];
            float r = colr * xv - tr[tx][b] + brv;
            float d = cold * xv - td[tx][b] + bdv;
            out[b * N + v] = tanhf(r) + d + xv;
        }
    }
}

extern "C" void kernel_launch(void* const* d_in, const int* in_sizes, int n_in,
                              void* d_out, int out_size, void* d_ws, size_t ws_size,
                              hipStream_t stream) {
    const float* x  = (const float*)d_in[1];
    const int*   ei = (const int*)d_in[2];
    const int*   ej = (const int*)d_in[3];
    const float* wr = (const float*)d_in[4];
    const float* wd = (const float*)d_in[5];
    const float* br = (const float*)d_in[6];
    const float* bd = (const float*)d_in[7];
    float* out = (float*)d_out;

    int E = in_sizes[2];
    int N = in_sizes[6];
    int NB = (N + BKT_NODES - 1) >> BKT_SHIFT;
    (void)out_size; (void)ws_size; (void)n_in;

    // workspace: xth[N*64 f16] | msg[2*N*64 f16] | colsum[2N f32] | gcur[2NB]
    //          | runs[2*NB*RCAP int2]   (~48 MB)
    char* w = (char*)d_ws;
    __half* xth = (__half*)w;    w += (size_t)N * 64 * 2;
    __half* msg = (__half*)w;    w += (size_t)2 * N * 64 * 2;
    float* colsum = (float*)w;   w += (size_t)2 * N * 4;
    int* gcur   = (int*)w;       w += (size_t)2 * NB * 4;
    w = (char*)(((uintptr_t)w + 15) & ~(uintptr_t)15);
    int2* runs  = (int2*)w;

    dim3 tb(64, 16);
    int ntiles = (N + 63) / 64;
    transpose_kernel<<<ntiles, tb, 0, stream>>>(x, xth, gcur, 2 * NB, N);

    int nchunks = (E + CH - 1) / CH;
    partition_kernel<<<nchunks, 512, 0, stream>>>(ei, ej, wr, wd, gcur, runs, E, NB);

    sortgather_kernel<<<2 * NB, 512, 0, stream>>>(gcur, runs, xth, msg, colsum, NB, N);

    final_kernel<<<ntiles, tb, 0, stream>>>(x, msg, colsum, br, bd, out, N);
}